// Round 18
// baseline (352.607 us; speedup 1.0000x reference)
//
#include <hip/hip_runtime.h>

#define NN 50000
#define EE 800000
#define NEP (EE + NN)
#define NBS 512                  // bnstats partial blocks
#define SCB 49                   // scan blocks: ceil(50000/1024)

typedef float f32x4 __attribute__((ext_vector_type(4)));
typedef float f32x2 __attribute__((ext_vector_type(2)));
typedef short bf16x8 __attribute__((ext_vector_type(8)));

__device__ inline float bf2f(unsigned short u) {
    union { unsigned int i; float f; } v; v.i = ((unsigned int)u) << 16; return v.f;
}
__device__ inline float lo2f(unsigned int u) {
    return __builtin_bit_cast(float, u << 16);
}
__device__ inline float hi2f(unsigned int u) {
    return __builtin_bit_cast(float, u & 0xFFFF0000u);
}
__device__ inline unsigned short f2bf(float f) {
    unsigned int x = __builtin_bit_cast(unsigned int, f);
    unsigned int r = x + 0x7FFFu + ((x >> 16) & 1u);
    return (unsigned short)(r >> 16);
}

#define XN4 1600000              // 50000*128/4
#define GPREP 6826               // (XN4 + 147456)/256
#define GEDGE 3321               // ceil(NEP/256)
#define GWAVE 12500              // ceil(NN/4)
#define GMAT  782                // ceil(NN/64)

// ---------------- merged prep: x->bf16 + L0 es/ed, W transposes, CSR pass 1 (4-way repl. counters) ----------------
__global__ __launch_bounds__(256) void k_prep(const float* __restrict__ x, unsigned short* __restrict__ xb,
        const float* __restrict__ W0, unsigned short* __restrict__ Wt0,
        const float* __restrict__ W1, unsigned short* __restrict__ Wt1,
        const float* __restrict__ W2, unsigned short* __restrict__ Wt2,
        const float* __restrict__ vs0, const float* __restrict__ vd0,
        float4* __restrict__ es4, float4* __restrict__ ed4,
        const int* __restrict__ ei, int* __restrict__ counts4, int* __restrict__ lps) {
    if (blockIdx.x >= GPREP) {               // CSR pass 1 (independent of prep work)
        int e = (blockIdx.x - GPREP) * 256 + threadIdx.x;
        if (e >= NEP) return;
        int dst = (e < EE) ? ei[EE + e] : (e - EE);
        int r = e & 3;
        lps[e] = atomicAdd(&counts4[r * NN + dst], 1);
        return;
    }
    int i = blockIdx.x * 256 + threadIdx.x;
    if (i < XN4) {
        // 32 consecutive lanes cover one row of 128 floats (4 each)
        float4 v = ((const float4*)x)[i];
        ushort4 o;
        o.x = f2bf(v.x); o.y = f2bf(v.y); o.z = f2bf(v.z); o.w = f2bf(v.w);
        ((ushort4*)xb)[i] = o;
        const int k0 = (i & 31) * 4;
        const float vv[4] = {v.x, v.y, v.z, v.w};
        float s[4] = {0.f, 0.f, 0.f, 0.f}, dd[4] = {0.f, 0.f, 0.f, 0.f};
        #pragma unroll
        for (int j = 0; j < 4; j++) {
            float f = vv[j];
            float4 a = *(const float4*)&vs0[(k0 + j) * 4];
            float4 b = *(const float4*)&vd0[(k0 + j) * 4];
            s[0] += f * a.x; s[1] += f * a.y; s[2] += f * a.z; s[3] += f * a.w;
            dd[0] += f * b.x; dd[1] += f * b.y; dd[2] += f * b.z; dd[3] += f * b.w;
        }
        #pragma unroll
        for (int d = 1; d < 32; d <<= 1) {
            #pragma unroll
            for (int j = 0; j < 4; j++) { s[j] += __shfl_xor(s[j], d); dd[j] += __shfl_xor(dd[j], d); }
        }
        if ((threadIdx.x & 31) == 0) {
            int row = i >> 5;
            es4[row] = make_float4(s[0], s[1], s[2], s[3]);
            ed4[row] = make_float4(dd[0], dd[1], dd[2], dd[3]);
        }
        return;
    }
    i -= XN4;
    if (i < 256 * 128) {           // Wt0[c][k] from W0[k][c]
        int c = i >> 7, k = i & 127;
        Wt0[i] = f2bf(W0[(size_t)k * 256 + c]);
        return;
    }
    i -= 256 * 128;
    if (i < 256 * 256) {
        int c = i >> 8, k = i & 255;
        Wt1[i] = f2bf(W1[(size_t)k * 256 + c]);
        return;
    }
    i -= 256 * 256;
    if (i < 192 * 256) {
        int c = i >> 8, k = i & 255;
        Wt2[i] = f2bf((c < 160) ? W2[(size_t)k * 160 + c] : 0.f);
    }
}

// ---------------- scan pass 1: fold 4 count planes -> totals; planes rewritten as replica offsets ----------------
__global__ __launch_bounds__(256) void k_scan1(int* __restrict__ counts4,
                                               int* __restrict__ indptr, int* __restrict__ bsum) {
    const int tid = threadIdx.x, lane = tid & 63, wid = tid >> 6;
    const int base = blockIdx.x * 1024 + tid * 4;
    int4 tot = make_int4(0, 0, 0, 0);
    if (base + 3 < NN) {
        int4 c0 = *(const int4*)&counts4[base];
        int4 c1 = *(const int4*)&counts4[NN + base];
        int4 c2 = *(const int4*)&counts4[2 * NN + base];
        int4 c3 = *(const int4*)&counts4[3 * NN + base];
        // replica exclusive offsets: plane0 <- 0, plane1 <- c0, plane2 <- c0+c1, plane3 <- c0+c1+c2
        int4 r2 = make_int4(c0.x + c1.x, c0.y + c1.y, c0.z + c1.z, c0.w + c1.w);
        int4 r3 = make_int4(r2.x + c2.x, r2.y + c2.y, r2.z + c2.z, r2.w + c2.w);
        tot = make_int4(r3.x + c3.x, r3.y + c3.y, r3.z + c3.z, r3.w + c3.w);
        *(int4*)&counts4[base]          = make_int4(0, 0, 0, 0);
        *(int4*)&counts4[NN + base]     = c0;
        *(int4*)&counts4[2 * NN + base] = r2;
        *(int4*)&counts4[3 * NN + base] = r3;
    } else {
        #pragma unroll
        for (int j = 0; j < 4; j++) {
            if (base + j < NN) {
                int c0 = counts4[base + j], c1 = counts4[NN + base + j];
                int c2 = counts4[2 * NN + base + j], c3 = counts4[3 * NN + base + j];
                counts4[base + j] = 0;
                counts4[NN + base + j] = c0;
                counts4[2 * NN + base + j] = c0 + c1;
                counts4[3 * NN + base + j] = c0 + c1 + c2;
                int t = c0 + c1 + c2 + c3;
                if (j == 0) tot.x = t; else if (j == 1) tot.y = t;
                else if (j == 2) tot.z = t; else tot.w = t;
            }
        }
    }
    int t = tot.x + tot.y + tot.z + tot.w;
    int s = t;
    #pragma unroll
    for (int d = 1; d < 64; d <<= 1) { int u = __shfl_up(s, d); if (lane >= d) s += u; }
    __shared__ int ws[4], wo[4];
    if (lane == 63) ws[wid] = s;
    __syncthreads();
    if (tid == 0) {
        int a = 0;
        #pragma unroll
        for (int j = 0; j < 4; j++) { wo[j] = a; a += ws[j]; }
        bsum[blockIdx.x] = a;
    }
    __syncthreads();
    int excl = wo[wid] + s - t;
    int p0 = excl, p1 = p0 + tot.x, p2 = p1 + tot.y, p3 = p2 + tot.z;
    if (base + 3 < NN) *(int4*)&indptr[base] = make_int4(p0, p1, p2, p3);
    else {
        if (base + 0 < NN) indptr[base + 0] = p0;
        if (base + 1 < NN) indptr[base + 1] = p1;
        if (base + 2 < NN) indptr[base + 2] = p2;
        if (base + 3 < NN) indptr[base + 3] = p3;
    }
}

// ---------------- hierarchical scan: pass 2 (scan block sums; write total) ----------------
__global__ __launch_bounds__(64) void k_scan2(int* __restrict__ bsum, int* __restrict__ indptr) {
    const int lane = threadIdx.x;
    int v = (lane < SCB) ? bsum[lane] : 0;
    int s = v;
    #pragma unroll
    for (int d = 1; d < 64; d <<= 1) { int u = __shfl_up(s, d); if (lane >= d) s += u; }
    if (lane < SCB) bsum[lane] = s - v;          // exclusive
    if (lane == SCB - 1) indptr[NN] = s;         // grand total
}

// ---------------- hierarchical scan: pass 3 (add block offsets) ----------------
__global__ __launch_bounds__(256) void k_scan3(int* __restrict__ indptr, const int* __restrict__ bsum) {
    const int base = blockIdx.x * 1024 + threadIdx.x * 4;
    const int off = bsum[blockIdx.x];
    if (off == 0) return;
    if (base + 3 < NN) {
        int4 v = *(const int4*)&indptr[base];
        v.x += off; v.y += off; v.z += off; v.w += off;
        *(int4*)&indptr[base] = v;
    } else {
        #pragma unroll
        for (int j = 0; j < 4; j++)
            if (base + j < NN) indptr[base + j] += off;
    }
}

// ---------------- merged: place src at final CSR position + dst run-length expansion ----------------
__global__ __launch_bounds__(256) void k_place(const int* __restrict__ ei,
                                               const int* __restrict__ indptr,
                                               const int* __restrict__ lps,
                                               const int* __restrict__ counts4,
                                               int* __restrict__ srcs,
                                               int* __restrict__ dstc) {
    if (blockIdx.x < GEDGE) {
        int e = blockIdx.x * 256 + threadIdx.x;
        if (e >= NEP) return;
        int src, dst;
        if (e < EE) { src = ei[e]; dst = ei[EE + e]; }
        else        { src = e - EE; dst = src; }
        int r = e & 3;
        srcs[indptr[dst] + counts4[r * NN + dst] + lps[e]] = src;
        return;
    }
    const int wid = threadIdx.x >> 6, lane = threadIdx.x & 63;
    const int n = (blockIdx.x - GEDGE) * 4 + wid;
    if (n >= NN) return;
    const int e0 = __builtin_amdgcn_readfirstlane(indptr[n]);
    const int e1 = __builtin_amdgcn_readfirstlane(indptr[n + 1]);
    for (int e = e0 + lane; e < e1; e += 64) dstc[e] = n;
}

// ---------------- fold attention vectors: v[k][h] = sum_c W[k, h*C+c] * a[h][c] ----------------
__global__ __launch_bounds__(256) void k_wv(
        const float* __restrict__ W0, const float* __restrict__ as0, const float* __restrict__ ad0,
        const float* __restrict__ W1, const float* __restrict__ as1, const float* __restrict__ ad1,
        const float* __restrict__ W2, const float* __restrict__ as2, const float* __restrict__ ad2,
        float* __restrict__ vs0, float* __restrict__ vd0,
        float* __restrict__ vs1, float* __restrict__ vd1,
        float* __restrict__ vs2, float* __restrict__ vd2) {
    int b = blockIdx.x;
    const float *W, *as_, *ad_; float *vs, *vd; int k, C, NO;
    if (b < 128)      { W = W0; as_ = as0; ad_ = ad0; vs = vs0; vd = vd0; k = b;       C = 64; NO = 256; }
    else if (b < 384) { W = W1; as_ = as1; ad_ = ad1; vs = vs1; vd = vd1; k = b - 128; C = 64; NO = 256; }
    else              { W = W2; as_ = as2; ad_ = ad2; vs = vs2; vd = vd2; k = b - 384; C = 40; NO = 160; }
    int h = threadIdx.x >> 6, c = threadIdx.x & 63;
    float s1 = 0.f, s2 = 0.f;
    if (c < C) {
        float wv = W[(size_t)k * NO + h * C + c];
        s1 = wv * as_[h * C + c];
        s2 = wv * ad_[h * C + c];
    }
    #pragma unroll
    for (int d = 1; d < 64; d <<= 1) { s1 += __shfl_xor(s1, d); s2 += __shfl_xor(s2, d); }
    if (c == 0) { vs[k * 4 + h] = s1; vd[k * 4 + h] = s2; }
}

// ---------------- bf16 MFMA GEMM (fp8 out) + appended edge-weight blocks ----------------
template<int K, int NOUTP, int NO>
__global__ __launch_bounds__(256) void k_gemm(const unsigned short* __restrict__ Xb,
                                              const unsigned short* __restrict__ Wt,
                                              unsigned char* __restrict__ Y,
                                              const float4* __restrict__ es4,
                                              const float4* __restrict__ ed4,
                                              const int* __restrict__ srcs,
                                              const int* __restrict__ dstc,
                                              uint2* __restrict__ wq) {
    if (blockIdx.x >= GMAT) {                 // edge-weight blocks (independent of GEMM)
        int p = (blockIdx.x - GMAT) * 256 + threadIdx.x;
        if (p >= NEP) return;
        float4 s = es4[srcs[p]];
        float4 d = ed4[dstc[p]];
        float e0 = s.x + d.x, e1 = s.y + d.y, e2 = s.z + d.z, e3 = s.w + d.w;
        e0 = (e0 > 0.f) ? e0 : 0.2f * e0;
        e1 = (e1 > 0.f) ? e1 : 0.2f * e1;
        e2 = (e2 > 0.f) ? e2 : 0.2f * e2;
        e3 = (e3 > 0.f) ? e3 : 0.2f * e3;
        uint2 o;
        o.x = (unsigned int)f2bf(__expf(e0)) | ((unsigned int)f2bf(__expf(e1)) << 16);
        o.y = (unsigned int)f2bf(__expf(e2)) | ((unsigned int)f2bf(__expf(e3)) << 16);
        wq[p] = o;
        return;
    }
    constexpr int G = K / 8;                       // 16B granules per row
    __shared__ __attribute__((aligned(16))) unsigned short As[64 * K];
    const int bm = blockIdx.x * 64;
    const int tid = threadIdx.x, lane = tid & 63, wid = tid >> 6;
    const int wm = wid >> 1, wn = wid & 1;
    const int l15 = lane & 15, l4 = lane >> 4;

    // linear LDS dest + swizzle applied on the per-lane GLOBAL source address
    #pragma unroll
    for (int i = 0; i < (64 * G) / 256; i++) {
        int p = tid + 256 * i;
        int row = p / G, g = p % G;
        int grow = bm + row; if (grow >= NN) grow = 0;
        int gsrc = g ^ (row & 7);
        const unsigned short* gp = &Xb[(size_t)grow * K + gsrc * 8];
        __builtin_amdgcn_global_load_lds(
            (const __attribute__((address_space(1))) void*)gp,
            (__attribute__((address_space(3))) void*)&As[p * 8],
            16, 0, 0);
    }
    __syncthreads();

    #pragma unroll
    for (int bg = 0; bg < NOUTP / 64; bg++) {
        const int bn = bg * 64;
        bf16x8 bfr[2][K / 32];
        #pragma unroll
        for (int n = 0; n < 2; n++) {
            const int col = bn + wn * 32 + n * 16 + l15;
            #pragma unroll
            for (int ks = 0; ks < K / 32; ks++)
                bfr[n][ks] = *(const bf16x8*)&Wt[(size_t)col * K + ks * 32 + l4 * 8];
        }
        f32x4 acc[2][2];
        #pragma unroll
        for (int m = 0; m < 2; m++)
            #pragma unroll
            for (int n = 0; n < 2; n++) acc[m][n] = (f32x4)0.f;
        #pragma unroll
        for (int ks = 0; ks < K / 32; ks++) {
            #pragma unroll
            for (int m = 0; m < 2; m++) {
                const int r = wm * 32 + m * 16 + l15;
                const int pg = ((ks << 2) + l4) ^ (r & 7);
                bf16x8 af = *(const bf16x8*)&As[r * K + pg * 8];
                #pragma unroll
                for (int n = 0; n < 2; n++)
                    acc[m][n] = __builtin_amdgcn_mfma_f32_16x16x32_bf16(af, bfr[n][ks], acc[m][n], 0, 0, 0);
            }
        }
        #pragma unroll
        for (int m = 0; m < 2; m++) {
            const int row0 = bm + wm * 32 + m * 16 + l4 * 4;
            #pragma unroll
            for (int n = 0; n < 2; n++) {
                const int col = bn + wn * 32 + n * 16 + l15;
                if (col >= NO) continue;
                #pragma unroll
                for (int j = 0; j < 4; j++) {
                    int gr = row0 + j;
                    if (gr >= NN) continue;
                    int pk = __builtin_amdgcn_cvt_pk_fp8_f32(acc[m][n][j], acc[m][n][j], 0, false);
                    Y[(size_t)gr * NOUTP + col] = (unsigned char)pk;
                }
            }
        }
    }
}

// ---------------- fused aggregation, layers 0/1 (wave/node, fp8 rows, packed decode) ----------------
__global__ __launch_bounds__(256) void k_agg(const unsigned char* __restrict__ H,
        const uint2* __restrict__ wq,
        const int* __restrict__ indptr, const int* __restrict__ srcs,
        unsigned short* __restrict__ outp) {
    const int wid = threadIdx.x >> 6, lane = threadIdx.x & 63;
    const int n = blockIdx.x * 4 + wid;
    if (n >= NN) return;
    const int head = lane >> 4;
    const int hw = head >> 1, hs = (head & 1) * 16;
    const int e0 = __builtin_amdgcn_readfirstlane(indptr[n]);
    const int e1 = __builtin_amdgcn_readfirstlane(indptr[n + 1]);
    float z = 0.f, a0 = 0.f, a1 = 0.f, a2 = 0.f, a3 = 0.f;
    const unsigned char* Hp = H + lane * 4;       // 4 fp8 cols per lane; row = 256 B
    int e = e0;
    for (; e + 8 <= e1; e += 8) {
        int s[8]; float ww[8];
        #pragma unroll
        for (int q = 0; q < 8; q++) {
            s[q] = srcs[e + q];
            uint2 w2 = wq[e + q];
            unsigned int wsv = hw ? w2.y : w2.x;
            ww[q] = bf2f((unsigned short)(wsv >> hs));
        }
        #pragma unroll
        for (int q = 0; q < 8; q++) {
            unsigned int hv = *(const unsigned int*)(Hp + (size_t)s[q] * 256);
            z += ww[q];
            f32x2 lo = __builtin_amdgcn_cvt_pk_f32_fp8(hv, false);
            f32x2 hi = __builtin_amdgcn_cvt_pk_f32_fp8(hv, true);
            a0 += ww[q] * lo[0]; a1 += ww[q] * lo[1];
            a2 += ww[q] * hi[0]; a3 += ww[q] * hi[1];
        }
    }
    for (; e < e1; ++e) {
        int s0 = srcs[e];
        uint2 w2 = wq[e];
        unsigned int wsv = hw ? w2.y : w2.x;
        float w0 = bf2f((unsigned short)(wsv >> hs));
        unsigned int hv = *(const unsigned int*)(Hp + (size_t)s0 * 256);
        z += w0;
        f32x2 lo = __builtin_amdgcn_cvt_pk_f32_fp8(hv, false);
        f32x2 hi = __builtin_amdgcn_cvt_pk_f32_fp8(hv, true);
        a0 += w0 * lo[0]; a1 += w0 * lo[1];
        a2 += w0 * hi[0]; a3 += w0 * hi[1];
    }
    float inv = 1.f / (z + 1e-16f);
    ushort4 o;
    o.x = f2bf(a0 * inv); o.y = f2bf(a1 * inv); o.z = f2bf(a2 * inv); o.w = f2bf(a3 * inv);
    *(ushort4*)&outp[(size_t)n * 256 + lane * 4] = o;
}

// ---------------- layer 2: aggregation + head-mean + bias + log_softmax (fp8 H2, stride 192B) ----------------
__global__ __launch_bounds__(256) void k_agg2(const unsigned char* __restrict__ H2,
        const uint2* __restrict__ wq,
        const int* __restrict__ indptr, const int* __restrict__ srcs,
        const float* __restrict__ b2, float* __restrict__ outp) {
    const int wid = threadIdx.x >> 6, lane = threadIdx.x & 63;
    const int n = blockIdx.x * 4 + wid;
    if (n >= NN) return;
    const bool act = lane < 40;
    const int head = lane / 10;
    const int hw = head >> 1, hs = (head & 1) * 16;
    const int e0 = __builtin_amdgcn_readfirstlane(indptr[n]);
    const int e1 = __builtin_amdgcn_readfirstlane(indptr[n + 1]);
    float z = 0.f, acc[4] = {0.f, 0.f, 0.f, 0.f};
    const unsigned char* Hp = H2 + lane * 4;      // 4 fp8 cols per active lane
    if (act) {
        int e = e0;
        for (; e + 8 <= e1; e += 8) {
            int s[8]; float ww[8];
            #pragma unroll
            for (int q = 0; q < 8; q++) {
                s[q] = srcs[e + q];
                uint2 w2 = wq[e + q];
                unsigned int wsv = hw ? w2.y : w2.x;
                ww[q] = bf2f((unsigned short)(wsv >> hs));
            }
            #pragma unroll
            for (int q = 0; q < 8; q++) {
                unsigned int hv = *(const unsigned int*)(Hp + (size_t)s[q] * 192);
                z += ww[q];
                f32x2 lo = __builtin_amdgcn_cvt_pk_f32_fp8(hv, false);
                f32x2 hi = __builtin_amdgcn_cvt_pk_f32_fp8(hv, true);
                acc[0] += ww[q] * lo[0]; acc[1] += ww[q] * lo[1];
                acc[2] += ww[q] * hi[0]; acc[3] += ww[q] * hi[1];
            }
        }
        for (; e < e1; ++e) {
            int s0 = srcs[e];
            uint2 w2 = wq[e];
            unsigned int wsv = hw ? w2.y : w2.x;
            float w0 = bf2f((unsigned short)(wsv >> hs));
            unsigned int hv = *(const unsigned int*)(Hp + (size_t)s0 * 192);
            z += w0;
            f32x2 lo = __builtin_amdgcn_cvt_pk_f32_fp8(hv, false);
            f32x2 hi = __builtin_amdgcn_cvt_pk_f32_fp8(hv, true);
            acc[0] += w0 * lo[0]; acc[1] += w0 * lo[1];
            acc[2] += w0 * hi[0]; acc[3] += w0 * hi[1];
        }
    }
    float inv = 1.f / (z + 1e-16f);
    float sv[4];
    #pragma unroll
    for (int j = 0; j < 4; j++) sv[j] = acc[j] * inv;
    #pragma unroll
    for (int j = 0; j < 4; j++) {
        float v = sv[j];
        v += __shfl(sv[j], lane + 10);
        v += __shfl(sv[j], lane + 20);
        v += __shfl(sv[j], lane + 30);
        sv[j] = v;
    }
    const bool ol = lane < 10;
    float m4 = -1e30f;
    #pragma unroll
    for (int j = 0; j < 4; j++) {
        sv[j] = ol ? (0.25f * sv[j] + b2[lane * 4 + j]) : -1e30f;
        m4 = fmaxf(m4, sv[j]);
    }
    #pragma unroll
    for (int d = 1; d < 16; d <<= 1) m4 = fmaxf(m4, __shfl_xor(m4, d));
    float s = 0.f;
    #pragma unroll
    for (int j = 0; j < 4; j++) s += ol ? __expf(sv[j] - m4) : 0.f;
    #pragma unroll
    for (int d = 1; d < 16; d <<= 1) s += __shfl_xor(s, d);
    float ls = logf(s);
    if (ol) {
        float4 o = make_float4(sv[0] - m4 - ls, sv[1] - m4 - ls, sv[2] - m4 - ls, sv[3] - m4 - ls);
        *(float4*)&outp[(size_t)n * 40 + lane * 4] = o;
    }
}

// ---------------- BN stats stage 1: per-block partials (NO atomics) ----------------
__global__ __launch_bounds__(256) void k_bnstats1(const unsigned short* __restrict__ X,
        float* __restrict__ ps, float* __restrict__ pq) {
    __shared__ float lds[4 * 256];
    const int tid = threadIdx.x;
    const int colg = (tid & 63) * 4;
    const int w = tid >> 6;
    float s[4] = {0.f, 0.f, 0.f, 0.f}, q[4] = {0.f, 0.f, 0.f, 0.f};
    for (int r = blockIdx.x * 4 + w; r < NN; r += NBS * 4) {
        ushort4 hv = *(const ushort4*)&X[(size_t)r * 256 + colg];
        const unsigned short hh[4] = {hv.x, hv.y, hv.z, hv.w};
        #pragma unroll
        for (int j = 0; j < 4; j++) { float v = bf2f(hh[j]); s[j] += v; q[j] += v * v; }
    }
    #pragma unroll
    for (int j = 0; j < 4; j++) lds[w * 256 + colg + j] = s[j];
    __syncthreads();
    float ts = lds[tid] + lds[256 + tid] + lds[512 + tid] + lds[768 + tid];
    __syncthreads();
    #pragma unroll
    for (int j = 0; j < 4; j++) lds[w * 256 + colg + j] = q[j];
    __syncthreads();
    float tq = lds[tid] + lds[256 + tid] + lds[512 + tid] + lds[768 + tid];
    ps[(size_t)blockIdx.x * 256 + tid] = ts;
    pq[(size_t)blockIdx.x * 256 + tid] = tq;
}

// ---------------- BN stats stage 2: reduce partials -> sc/sh per column ----------------
__global__ __launch_bounds__(256) void k_bnred(const float* __restrict__ ps,
        const float* __restrict__ pq, const float* __restrict__ g,
        const float* __restrict__ beta, float* __restrict__ sc_o, float* __restrict__ sh_o) {
    const int col = blockIdx.x, tid = threadIdx.x;
    float s = ps[(size_t)tid * 256 + col] + ps[(size_t)(tid + 256) * 256 + col];
    float q = pq[(size_t)tid * 256 + col] + pq[(size_t)(tid + 256) * 256 + col];
    #pragma unroll
    for (int d = 1; d < 64; d <<= 1) { s += __shfl_xor(s, d); q += __shfl_xor(q, d); }
    __shared__ float ls[4], lq[4];
    if ((tid & 63) == 0) { ls[tid >> 6] = s; lq[tid >> 6] = q; }
    __syncthreads();
    if (tid == 0) {
        float S = ls[0] + ls[1] + ls[2] + ls[3];
        float Q = lq[0] + lq[1] + lq[2] + lq[3];
        const float inv = 1.f / (float)NN;
        float mu = S * inv;
        float var = Q * inv - mu * mu;
        float sc = rsqrtf(var + 1e-5f) * g[col];
        sc_o[col] = sc;
        sh_o[col] = beta[col] - mu * sc;             // GAT bias b cancels under BN
    }
}

// ---------------- BN apply + ELU in-place (bf16) + NEXT layer's es/ed ----------------
__global__ __launch_bounds__(256) void k_bnapply(unsigned short* __restrict__ X,
        const float* __restrict__ sc_i, const float* __restrict__ sh_i,
        const float* __restrict__ vs, const float* __restrict__ vd,
        float4* __restrict__ es4, float4* __restrict__ ed4) {
    const int hl = threadIdx.x & 31;
    const int colg = hl * 8;
    const int rowo = threadIdx.x >> 5;
    float sc[8], sh[8];
    #pragma unroll
    for (int j = 0; j < 8; j++) { sc[j] = sc_i[colg + j]; sh[j] = sh_i[colg + j]; }
    for (int r = blockIdx.x * 8 + rowo; r < NN; r += gridDim.x * 8) {
        uint4 u = *(uint4*)&X[(size_t)r * 256 + colg];
        unsigned int uu[4] = {u.x, u.y, u.z, u.w};
        unsigned int oo[4];
        float s[4] = {0.f, 0.f, 0.f, 0.f}, dd[4] = {0.f, 0.f, 0.f, 0.f};
        #pragma unroll
        for (int p = 0; p < 4; p++) {
            float lo = lo2f(uu[p]);
            float hi = hi2f(uu[p]);
            float vlo = lo * sc[p * 2] + sh[p * 2];
            float vhi = hi * sc[p * 2 + 1] + sh[p * 2 + 1];
            vlo = (vlo > 0.f) ? vlo : expm1f(vlo);
            vhi = (vhi > 0.f) ? vhi : expm1f(vhi);
            oo[p] = (unsigned int)f2bf(vlo) | ((unsigned int)f2bf(vhi) << 16);
            // next-layer logits contribution
            float4 a0 = *(const float4*)&vs[(colg + 2 * p) * 4];
            float4 b0 = *(const float4*)&vd[(colg + 2 * p) * 4];
            float4 a1 = *(const float4*)&vs[(colg + 2 * p + 1) * 4];
            float4 b1 = *(const float4*)&vd[(colg + 2 * p + 1) * 4];
            s[0] += vlo * a0.x + vhi * a1.x; s[1] += vlo * a0.y + vhi * a1.y;
            s[2] += vlo * a0.z + vhi * a1.z; s[3] += vlo * a0.w + vhi * a1.w;
            dd[0] += vlo * b0.x + vhi * b1.x; dd[1] += vlo * b0.y + vhi * b1.y;
            dd[2] += vlo * b0.z + vhi * b1.z; dd[3] += vlo * b0.w + vhi * b1.w;
        }
        *(uint4*)&X[(size_t)r * 256 + colg] = make_uint4(oo[0], oo[1], oo[2], oo[3]);
        #pragma unroll
        for (int d = 1; d < 32; d <<= 1) {
            #pragma unroll
            for (int j = 0; j < 4; j++) { s[j] += __shfl_xor(s[j], d); dd[j] += __shfl_xor(dd[j], d); }
        }
        if (hl == 0) {
            es4[r] = make_float4(s[0], s[1], s[2], s[3]);
            ed4[r] = make_float4(dd[0], dd[1], dd[2], dd[3]);
        }
    }
}

extern "C" void kernel_launch(void* const* d_in, const int* in_sizes, int n_in,
                              void* d_out, int out_size, void* d_ws, size_t ws_size,
                              hipStream_t stream) {
    const float* x   = (const float*)d_in[0];
    const int*   ei  = (const int*)d_in[1];
    const float* W0  = (const float*)d_in[2];
    const float* as0 = (const float*)d_in[3];
    const float* ad0 = (const float*)d_in[4];
    const float* g0  = (const float*)d_in[6];
    const float* be0 = (const float*)d_in[7];
    const float* W1  = (const float*)d_in[8];
    const float* as1 = (const float*)d_in[9];
    const float* ad1 = (const float*)d_in[10];
    const float* g1  = (const float*)d_in[12];
    const float* be1 = (const float*)d_in[13];
    const float* W2  = (const float*)d_in[14];
    const float* as2 = (const float*)d_in[15];
    const float* ad2 = (const float*)d_in[16];
    const float* b2  = (const float*)d_in[17];
    float* out = (float*)d_out;

    char* w = (char*)d_ws;
    size_t off = 0;
    auto take = [&](size_t bytes) -> void* {
        off = (off + 255) & ~(size_t)255;
        void* p = w + off; off += bytes; return p;
    };
    unsigned short* Agg16 = (unsigned short*)take((size_t)NN * 256 * 2);  // agg out / BN in-place
    unsigned short* xb    = (unsigned short*)take((size_t)NN * 128 * 2);
    unsigned char*  H8    = (unsigned char*)take((size_t)NN * 256);       // fp8 H: L0/L1 stride 256B, L2 stride 192B
    float* es     = (float*)take((size_t)NN * 4 * 4);
    float* ed     = (float*)take((size_t)NN * 4 * 4);
    int*   counts4 = (int*)take((size_t)4 * NN * 4);     // 4 replicated planes -> replica offsets
    int*   indptr = (int*)take((size_t)(NN + 1) * 4);
    int*   lps    = (int*)take((size_t)NEP * 4);
    int*   srcs   = (int*)take((size_t)NEP * 4);
    int*   dstc   = (int*)take((size_t)NEP * 4);
    uint2* wq     = (uint2*)take((size_t)NEP * 8);
    int*   bsum   = (int*)take(64 * 4);
    unsigned short* Wt0 = (unsigned short*)take((size_t)256 * 128 * 2);
    unsigned short* Wt1 = (unsigned short*)take((size_t)256 * 256 * 2);
    unsigned short* Wt2 = (unsigned short*)take((size_t)192 * 256 * 2);
    float* vs0 = (float*)take(128 * 4 * 4);
    float* vd0 = (float*)take(128 * 4 * 4);
    float* vs1 = (float*)take(256 * 4 * 4);
    float* vd1 = (float*)take(256 * 4 * 4);
    float* vs2 = (float*)take(256 * 4 * 4);
    float* vd2 = (float*)take(256 * 4 * 4);
    float* ps  = (float*)take((size_t)NBS * 256 * 4);
    float* pq  = (float*)take((size_t)NBS * 256 * 4);
    float* bns = (float*)take(512 * 4);                  // sc[256] | sh[256]

    k_wv<<<640, 256, 0, stream>>>(W0, as0, ad0, W1, as1, ad1, W2, as2, ad2,
                                  vs0, vd0, vs1, vd1, vs2, vd2);
    hipMemsetAsync(counts4, 0, (size_t)4 * NN * 4, stream);
    k_prep<<<GPREP + GEDGE, 256, 0, stream>>>(x, xb, W0, Wt0, W1, Wt1, W2, Wt2,
                                              vs0, vd0, (float4*)es, (float4*)ed,
                                              ei, counts4, lps);
    k_scan1<<<SCB, 256, 0, stream>>>(counts4, indptr, bsum);
    k_scan2<<<1, 64, 0, stream>>>(bsum, indptr);
    k_scan3<<<SCB, 256, 0, stream>>>(indptr, bsum);
    k_place<<<GEDGE + GWAVE, 256, 0, stream>>>(ei, indptr, lps, counts4, srcs, dstc);

    // ---- layer 0 ----  (es/ed from k_prep; H in fp8; wgt fused into gemm grid)
    k_gemm<128, 256, 256><<<GMAT + GEDGE, 256, 0, stream>>>(xb, Wt0, H8,
            (const float4*)es, (const float4*)ed, srcs, dstc, wq);
    k_agg<<<GWAVE, 256, 0, stream>>>(H8, wq, indptr, srcs, Agg16);
    k_bnstats1<<<NBS, 256, 0, stream>>>(Agg16, ps, pq);
    k_bnred<<<256, 256, 0, stream>>>(ps, pq, g0, be0, bns, bns + 256);
    k_bnapply<<<1024, 256, 0, stream>>>(Agg16, bns, bns + 256, vs1, vd1,
                                        (float4*)es, (float4*)ed);

    // ---- layer 1 ----
    k_gemm<256, 256, 256><<<GMAT + GEDGE, 256, 0, stream>>>(Agg16, Wt1, H8,
            (const float4*)es, (const float4*)ed, srcs, dstc, wq);
    k_agg<<<GWAVE, 256, 0, stream>>>(H8, wq, indptr, srcs, Agg16);
    k_bnstats1<<<NBS, 256, 0, stream>>>(Agg16, ps, pq);
    k_bnred<<<256, 256, 0, stream>>>(ps, pq, g1, be1, bns, bns + 256);
    k_bnapply<<<1024, 256, 0, stream>>>(Agg16, bns, bns + 256, vs2, vd2,
                                        (float4*)es, (float4*)ed);

    // ---- layer 2 ----  (H in fp8, row stride 192B, 160 cols used)
    k_gemm<256, 192, 160><<<GMAT + GEDGE, 256, 0, stream>>>(Agg16, Wt2, H8,
            (const float4*)es, (const float4*)ed, srcs, dstc, wq);
    k_agg2<<<GWAVE, 256, 0, stream>>>(H8, wq, indptr, srcs, b2, out);
}

// Round 19
// 343.780 us; speedup vs baseline: 1.0257x; 1.0257x over previous
//
#include <hip/hip_runtime.h>

#define NN 50000
#define EE 800000
#define NEP (EE + NN)
#define NBS 512                  // bnstats partial blocks
#define SCB 49                   // scan blocks: ceil(50000/1024)

typedef float f32x4 __attribute__((ext_vector_type(4)));
typedef float f32x2 __attribute__((ext_vector_type(2)));
typedef short bf16x8 __attribute__((ext_vector_type(8)));

__device__ inline float bf2f(unsigned short u) {
    union { unsigned int i; float f; } v; v.i = ((unsigned int)u) << 16; return v.f;
}
__device__ inline float lo2f(unsigned int u) {
    return __builtin_bit_cast(float, u << 16);
}
__device__ inline float hi2f(unsigned int u) {
    return __builtin_bit_cast(float, u & 0xFFFF0000u);
}
__device__ inline unsigned short f2bf(float f) {
    unsigned int x = __builtin_bit_cast(unsigned int, f);
    unsigned int r = x + 0x7FFFu + ((x >> 16) & 1u);
    return (unsigned short)(r >> 16);
}

#define XN4 1600000              // 50000*128/4
#define GPREP 6826               // (XN4 + 147456)/256
#define GEDGE 3321               // ceil(NEP/256)
#define GWAVE 12500              // ceil(NN/4)
#define GMAT  782                // ceil(NN/64)

// ---------------- prep: x->bf16 + L0 es/ed, W transposes ----------------
__global__ __launch_bounds__(256) void k_prep(const float* __restrict__ x, unsigned short* __restrict__ xb,
        const float* __restrict__ W0, unsigned short* __restrict__ Wt0,
        const float* __restrict__ W1, unsigned short* __restrict__ Wt1,
        const float* __restrict__ W2, unsigned short* __restrict__ Wt2,
        const float* __restrict__ vs0, const float* __restrict__ vd0,
        float4* __restrict__ es4, float4* __restrict__ ed4) {
    int i = blockIdx.x * 256 + threadIdx.x;
    if (i < XN4) {
        // 32 consecutive lanes cover one row of 128 floats (4 each)
        float4 v = ((const float4*)x)[i];
        ushort4 o;
        o.x = f2bf(v.x); o.y = f2bf(v.y); o.z = f2bf(v.z); o.w = f2bf(v.w);
        ((ushort4*)xb)[i] = o;
        const int k0 = (i & 31) * 4;
        const float vv[4] = {v.x, v.y, v.z, v.w};
        float s[4] = {0.f, 0.f, 0.f, 0.f}, dd[4] = {0.f, 0.f, 0.f, 0.f};
        #pragma unroll
        for (int j = 0; j < 4; j++) {
            float f = vv[j];
            float4 a = *(const float4*)&vs0[(k0 + j) * 4];
            float4 b = *(const float4*)&vd0[(k0 + j) * 4];
            s[0] += f * a.x; s[1] += f * a.y; s[2] += f * a.z; s[3] += f * a.w;
            dd[0] += f * b.x; dd[1] += f * b.y; dd[2] += f * b.z; dd[3] += f * b.w;
        }
        #pragma unroll
        for (int d = 1; d < 32; d <<= 1) {
            #pragma unroll
            for (int j = 0; j < 4; j++) { s[j] += __shfl_xor(s[j], d); dd[j] += __shfl_xor(dd[j], d); }
        }
        if ((threadIdx.x & 31) == 0) {
            int row = i >> 5;
            es4[row] = make_float4(s[0], s[1], s[2], s[3]);
            ed4[row] = make_float4(dd[0], dd[1], dd[2], dd[3]);
        }
        return;
    }
    i -= XN4;
    if (i < 256 * 128) {           // Wt0[c][k] from W0[k][c]
        int c = i >> 7, k = i & 127;
        Wt0[i] = f2bf(W0[(size_t)k * 256 + c]);
        return;
    }
    i -= 256 * 128;
    if (i < 256 * 256) {
        int c = i >> 8, k = i & 255;
        Wt1[i] = f2bf(W1[(size_t)k * 256 + c]);
        return;
    }
    i -= 256 * 256;
    if (i < 192 * 256) {
        int c = i >> 8, k = i & 255;
        Wt2[i] = f2bf((c < 160) ? W2[(size_t)k * 160 + c] : 0.f);
    }
}

// ---------------- hierarchical scan: pass 1 (per-block exclusive + block sums) ----------------
__global__ __launch_bounds__(256) void k_scan1(const int* __restrict__ counts,
                                               int* __restrict__ indptr, int* __restrict__ bsum) {
    const int tid = threadIdx.x, lane = tid & 63, wid = tid >> 6;
    const int base = blockIdx.x * 1024 + tid * 4;
    int4 v = make_int4(0, 0, 0, 0);
    if (base + 3 < NN) v = *(const int4*)&counts[base];
    else {
        if (base + 0 < NN) v.x = counts[base + 0];
        if (base + 1 < NN) v.y = counts[base + 1];
        if (base + 2 < NN) v.z = counts[base + 2];
        if (base + 3 < NN) v.w = counts[base + 3];
    }
    int t = v.x + v.y + v.z + v.w;
    int s = t;
    #pragma unroll
    for (int d = 1; d < 64; d <<= 1) { int u = __shfl_up(s, d); if (lane >= d) s += u; }
    __shared__ int ws[4], wo[4];
    if (lane == 63) ws[wid] = s;
    __syncthreads();
    if (tid == 0) {
        int a = 0;
        #pragma unroll
        for (int j = 0; j < 4; j++) { wo[j] = a; a += ws[j]; }
        bsum[blockIdx.x] = a;
    }
    __syncthreads();
    int excl = wo[wid] + s - t;
    int p0 = excl, p1 = p0 + v.x, p2 = p1 + v.y, p3 = p2 + v.z;
    if (base + 3 < NN) *(int4*)&indptr[base] = make_int4(p0, p1, p2, p3);
    else {
        if (base + 0 < NN) indptr[base + 0] = p0;
        if (base + 1 < NN) indptr[base + 1] = p1;
        if (base + 2 < NN) indptr[base + 2] = p2;
        if (base + 3 < NN) indptr[base + 3] = p3;
    }
}

// ---------------- hierarchical scan: pass 2 (scan block sums; write total) ----------------
__global__ __launch_bounds__(64) void k_scan2(int* __restrict__ bsum, int* __restrict__ indptr) {
    const int lane = threadIdx.x;
    int v = (lane < SCB) ? bsum[lane] : 0;
    int s = v;
    #pragma unroll
    for (int d = 1; d < 64; d <<= 1) { int u = __shfl_up(s, d); if (lane >= d) s += u; }
    if (lane < SCB) bsum[lane] = s - v;          // exclusive
    if (lane == SCB - 1) indptr[NN] = s;         // grand total
}

// ---------------- hierarchical scan: pass 3 (add block offsets) ----------------
__global__ __launch_bounds__(256) void k_scan3(int* __restrict__ indptr, const int* __restrict__ bsum) {
    const int base = blockIdx.x * 1024 + threadIdx.x * 4;
    const int off = bsum[blockIdx.x];
    if (off == 0) return;
    if (base + 3 < NN) {
        int4 v = *(const int4*)&indptr[base];
        v.x += off; v.y += off; v.z += off; v.w += off;
        *(int4*)&indptr[base] = v;
    } else {
        #pragma unroll
        for (int j = 0; j < 4; j++)
            if (base + j < NN) indptr[base + j] += off;
    }
}

// ---------------- merged: place src at final CSR position + dst run-length expansion ----------------
__global__ __launch_bounds__(256) void k_place(const int* __restrict__ ei,
                                               const int* __restrict__ indptr,
                                               const int* __restrict__ lps,
                                               int* __restrict__ srcs,
                                               int* __restrict__ dstc) {
    if (blockIdx.x < GEDGE) {
        int e = blockIdx.x * 256 + threadIdx.x;
        if (e >= NEP) return;
        int src, dst;
        if (e < EE) { src = ei[e]; dst = ei[EE + e]; }
        else        { src = e - EE; dst = src; }
        srcs[indptr[dst] + lps[e]] = src;
        return;
    }
    const int wid = threadIdx.x >> 6, lane = threadIdx.x & 63;
    const int n = (blockIdx.x - GEDGE) * 4 + wid;
    if (n >= NN) return;
    const int e0 = __builtin_amdgcn_readfirstlane(indptr[n]);
    const int e1 = __builtin_amdgcn_readfirstlane(indptr[n + 1]);
    for (int e = e0 + lane; e < e1; e += 64) dstc[e] = n;
}

// ---------------- standalone edge weights (L0) ----------------
__global__ __launch_bounds__(256) void k_wgt(const float4* __restrict__ es4,
        const float4* __restrict__ ed4, const int* __restrict__ srcs,
        const int* __restrict__ dstc, uint2* __restrict__ wq) {
    int p = blockIdx.x * 256 + threadIdx.x;
    if (p >= NEP) return;
    float4 s = es4[srcs[p]];
    float4 d = ed4[dstc[p]];
    float e0 = s.x + d.x, e1 = s.y + d.y, e2 = s.z + d.z, e3 = s.w + d.w;
    e0 = (e0 > 0.f) ? e0 : 0.2f * e0;
    e1 = (e1 > 0.f) ? e1 : 0.2f * e1;
    e2 = (e2 > 0.f) ? e2 : 0.2f * e2;
    e3 = (e3 > 0.f) ? e3 : 0.2f * e3;
    uint2 o;
    o.x = (unsigned int)f2bf(__expf(e0)) | ((unsigned int)f2bf(__expf(e1)) << 16);
    o.y = (unsigned int)f2bf(__expf(e2)) | ((unsigned int)f2bf(__expf(e3)) << 16);
    wq[p] = o;
}

// ---------------- fold attention vectors: v[k][h] = sum_c W[k, h*C+c] * a[h][c] ----------------
__global__ __launch_bounds__(256) void k_wv(
        const float* __restrict__ W0, const float* __restrict__ as0, const float* __restrict__ ad0,
        const float* __restrict__ W1, const float* __restrict__ as1, const float* __restrict__ ad1,
        const float* __restrict__ W2, const float* __restrict__ as2, const float* __restrict__ ad2,
        float* __restrict__ vs0, float* __restrict__ vd0,
        float* __restrict__ vs1, float* __restrict__ vd1,
        float* __restrict__ vs2, float* __restrict__ vd2) {
    int b = blockIdx.x;
    const float *W, *as_, *ad_; float *vs, *vd; int k, C, NO;
    if (b < 128)      { W = W0; as_ = as0; ad_ = ad0; vs = vs0; vd = vd0; k = b;       C = 64; NO = 256; }
    else if (b < 384) { W = W1; as_ = as1; ad_ = ad1; vs = vs1; vd = vd1; k = b - 128; C = 64; NO = 256; }
    else              { W = W2; as_ = as2; ad_ = ad2; vs = vs2; vd = vd2; k = b - 384; C = 40; NO = 160; }
    int h = threadIdx.x >> 6, c = threadIdx.x & 63;
    float s1 = 0.f, s2 = 0.f;
    if (c < C) {
        float wv = W[(size_t)k * NO + h * C + c];
        s1 = wv * as_[h * C + c];
        s2 = wv * ad_[h * C + c];
    }
    #pragma unroll
    for (int d = 1; d < 64; d <<= 1) { s1 += __shfl_xor(s1, d); s2 += __shfl_xor(s2, d); }
    if (c == 0) { vs[k * 4 + h] = s1; vd[k * 4 + h] = s2; }
}

// ---------------- bf16 MFMA GEMM (fp8 out) + appended blocks: CSR pass-1 (L0) or edge weights (L1/L2) ----------------
template<int K, int NOUTP, int NO, bool CSPASS>
__global__ __launch_bounds__(256) void k_gemm(const unsigned short* __restrict__ Xb,
                                              const unsigned short* __restrict__ Wt,
                                              unsigned char* __restrict__ Y,
                                              const float4* __restrict__ es4,
                                              const float4* __restrict__ ed4,
                                              const int* __restrict__ srcs,
                                              const int* __restrict__ dstc,
                                              uint2* __restrict__ wq,
                                              const int* __restrict__ ei,
                                              int* __restrict__ counts,
                                              int* __restrict__ lps) {
    if (blockIdx.x >= GMAT) {                 // appended blocks (independent of GEMM)
        int p = (blockIdx.x - GMAT) * 256 + threadIdx.x;
        if (p >= NEP) return;
        if constexpr (CSPASS) {               // CSR pass 1: per-dst local position
            int dst = (p < EE) ? ei[EE + p] : (p - EE);
            lps[p] = atomicAdd(&counts[dst], 1);
        } else {                              // edge softmax weights
            float4 s = es4[srcs[p]];
            float4 d = ed4[dstc[p]];
            float e0 = s.x + d.x, e1 = s.y + d.y, e2 = s.z + d.z, e3 = s.w + d.w;
            e0 = (e0 > 0.f) ? e0 : 0.2f * e0;
            e1 = (e1 > 0.f) ? e1 : 0.2f * e1;
            e2 = (e2 > 0.f) ? e2 : 0.2f * e2;
            e3 = (e3 > 0.f) ? e3 : 0.2f * e3;
            uint2 o;
            o.x = (unsigned int)f2bf(__expf(e0)) | ((unsigned int)f2bf(__expf(e1)) << 16);
            o.y = (unsigned int)f2bf(__expf(e2)) | ((unsigned int)f2bf(__expf(e3)) << 16);
            wq[p] = o;
        }
        return;
    }
    constexpr int G = K / 8;                       // 16B granules per row
    __shared__ __attribute__((aligned(16))) unsigned short As[64 * K];
    const int bm = blockIdx.x * 64;
    const int tid = threadIdx.x, lane = tid & 63, wid = tid >> 6;
    const int wm = wid >> 1, wn = wid & 1;
    const int l15 = lane & 15, l4 = lane >> 4;

    // linear LDS dest + swizzle applied on the per-lane GLOBAL source address
    #pragma unroll
    for (int i = 0; i < (64 * G) / 256; i++) {
        int p = tid + 256 * i;
        int row = p / G, g = p % G;
        int grow = bm + row; if (grow >= NN) grow = 0;
        int gsrc = g ^ (row & 7);
        const unsigned short* gp = &Xb[(size_t)grow * K + gsrc * 8];
        __builtin_amdgcn_global_load_lds(
            (const __attribute__((address_space(1))) void*)gp,
            (__attribute__((address_space(3))) void*)&As[p * 8],
            16, 0, 0);
    }
    __syncthreads();

    #pragma unroll
    for (int bg = 0; bg < NOUTP / 64; bg++) {
        const int bn = bg * 64;
        bf16x8 bfr[2][K / 32];
        #pragma unroll
        for (int n = 0; n < 2; n++) {
            const int col = bn + wn * 32 + n * 16 + l15;
            #pragma unroll
            for (int ks = 0; ks < K / 32; ks++)
                bfr[n][ks] = *(const bf16x8*)&Wt[(size_t)col * K + ks * 32 + l4 * 8];
        }
        f32x4 acc[2][2];
        #pragma unroll
        for (int m = 0; m < 2; m++)
            #pragma unroll
            for (int n = 0; n < 2; n++) acc[m][n] = (f32x4)0.f;
        #pragma unroll
        for (int ks = 0; ks < K / 32; ks++) {
            #pragma unroll
            for (int m = 0; m < 2; m++) {
                const int r = wm * 32 + m * 16 + l15;
                const int pg = ((ks << 2) + l4) ^ (r & 7);
                bf16x8 af = *(const bf16x8*)&As[r * K + pg * 8];
                #pragma unroll
                for (int n = 0; n < 2; n++)
                    acc[m][n] = __builtin_amdgcn_mfma_f32_16x16x32_bf16(af, bfr[n][ks], acc[m][n], 0, 0, 0);
            }
        }
        #pragma unroll
        for (int m = 0; m < 2; m++) {
            const int row0 = bm + wm * 32 + m * 16 + l4 * 4;
            #pragma unroll
            for (int n = 0; n < 2; n++) {
                const int col = bn + wn * 32 + n * 16 + l15;
                if (col >= NO) continue;
                #pragma unroll
                for (int j = 0; j < 4; j++) {
                    int gr = row0 + j;
                    if (gr >= NN) continue;
                    int pk = __builtin_amdgcn_cvt_pk_fp8_f32(acc[m][n][j], acc[m][n][j], 0, false);
                    Y[(size_t)gr * NOUTP + col] = (unsigned char)pk;
                }
            }
        }
    }
}

// ---------------- fused aggregation, layers 0/1 (wave/node, fp8 rows, packed decode) ----------------
__global__ __launch_bounds__(256) void k_agg(const unsigned char* __restrict__ H,
        const uint2* __restrict__ wq,
        const int* __restrict__ indptr, const int* __restrict__ srcs,
        unsigned short* __restrict__ outp) {
    const int wid = threadIdx.x >> 6, lane = threadIdx.x & 63;
    const int n = blockIdx.x * 4 + wid;
    if (n >= NN) return;
    const int head = lane >> 4;
    const int hw = head >> 1, hs = (head & 1) * 16;
    const int e0 = __builtin_amdgcn_readfirstlane(indptr[n]);
    const int e1 = __builtin_amdgcn_readfirstlane(indptr[n + 1]);
    float z = 0.f, a0 = 0.f, a1 = 0.f, a2 = 0.f, a3 = 0.f;
    const unsigned char* Hp = H + lane * 4;       // 4 fp8 cols per lane; row = 256 B
    int e = e0;
    for (; e + 8 <= e1; e += 8) {
        int s[8]; float ww[8];
        #pragma unroll
        for (int q = 0; q < 8; q++) {
            s[q] = srcs[e + q];
            uint2 w2 = wq[e + q];
            unsigned int wsv = hw ? w2.y : w2.x;
            ww[q] = bf2f((unsigned short)(wsv >> hs));
        }
        #pragma unroll
        for (int q = 0; q < 8; q++) {
            unsigned int hv = *(const unsigned int*)(Hp + (size_t)s[q] * 256);
            z += ww[q];
            f32x2 lo = __builtin_amdgcn_cvt_pk_f32_fp8(hv, false);
            f32x2 hi = __builtin_amdgcn_cvt_pk_f32_fp8(hv, true);
            a0 += ww[q] * lo[0]; a1 += ww[q] * lo[1];
            a2 += ww[q] * hi[0]; a3 += ww[q] * hi[1];
        }
    }
    for (; e < e1; ++e) {
        int s0 = srcs[e];
        uint2 w2 = wq[e];
        unsigned int wsv = hw ? w2.y : w2.x;
        float w0 = bf2f((unsigned short)(wsv >> hs));
        unsigned int hv = *(const unsigned int*)(Hp + (size_t)s0 * 256);
        z += w0;
        f32x2 lo = __builtin_amdgcn_cvt_pk_f32_fp8(hv, false);
        f32x2 hi = __builtin_amdgcn_cvt_pk_f32_fp8(hv, true);
        a0 += w0 * lo[0]; a1 += w0 * lo[1];
        a2 += w0 * hi[0]; a3 += w0 * hi[1];
    }
    float inv = 1.f / (z + 1e-16f);
    ushort4 o;
    o.x = f2bf(a0 * inv); o.y = f2bf(a1 * inv); o.z = f2bf(a2 * inv); o.w = f2bf(a3 * inv);
    *(ushort4*)&outp[(size_t)n * 256 + lane * 4] = o;
}

// ---------------- layer 2: aggregation + head-mean + bias + log_softmax (fp8 H2, stride 192B) ----------------
__global__ __launch_bounds__(256) void k_agg2(const unsigned char* __restrict__ H2,
        const uint2* __restrict__ wq,
        const int* __restrict__ indptr, const int* __restrict__ srcs,
        const float* __restrict__ b2, float* __restrict__ outp) {
    const int wid = threadIdx.x >> 6, lane = threadIdx.x & 63;
    const int n = blockIdx.x * 4 + wid;
    if (n >= NN) return;
    const bool act = lane < 40;
    const int head = lane / 10;
    const int hw = head >> 1, hs = (head & 1) * 16;
    const int e0 = __builtin_amdgcn_readfirstlane(indptr[n]);
    const int e1 = __builtin_amdgcn_readfirstlane(indptr[n + 1]);
    float z = 0.f, acc[4] = {0.f, 0.f, 0.f, 0.f};
    const unsigned char* Hp = H2 + lane * 4;      // 4 fp8 cols per active lane
    if (act) {
        int e = e0;
        for (; e + 8 <= e1; e += 8) {
            int s[8]; float ww[8];
            #pragma unroll
            for (int q = 0; q < 8; q++) {
                s[q] = srcs[e + q];
                uint2 w2 = wq[e + q];
                unsigned int wsv = hw ? w2.y : w2.x;
                ww[q] = bf2f((unsigned short)(wsv >> hs));
            }
            #pragma unroll
            for (int q = 0; q < 8; q++) {
                unsigned int hv = *(const unsigned int*)(Hp + (size_t)s[q] * 192);
                z += ww[q];
                f32x2 lo = __builtin_amdgcn_cvt_pk_f32_fp8(hv, false);
                f32x2 hi = __builtin_amdgcn_cvt_pk_f32_fp8(hv, true);
                acc[0] += ww[q] * lo[0]; acc[1] += ww[q] * lo[1];
                acc[2] += ww[q] * hi[0]; acc[3] += ww[q] * hi[1];
            }
        }
        for (; e < e1; ++e) {
            int s0 = srcs[e];
            uint2 w2 = wq[e];
            unsigned int wsv = hw ? w2.y : w2.x;
            float w0 = bf2f((unsigned short)(wsv >> hs));
            unsigned int hv = *(const unsigned int*)(Hp + (size_t)s0 * 192);
            z += w0;
            f32x2 lo = __builtin_amdgcn_cvt_pk_f32_fp8(hv, false);
            f32x2 hi = __builtin_amdgcn_cvt_pk_f32_fp8(hv, true);
            acc[0] += w0 * lo[0]; acc[1] += w0 * lo[1];
            acc[2] += w0 * hi[0]; acc[3] += w0 * hi[1];
        }
    }
    float inv = 1.f / (z + 1e-16f);
    float sv[4];
    #pragma unroll
    for (int j = 0; j < 4; j++) sv[j] = acc[j] * inv;
    #pragma unroll
    for (int j = 0; j < 4; j++) {
        float v = sv[j];
        v += __shfl(sv[j], lane + 10);
        v += __shfl(sv[j], lane + 20);
        v += __shfl(sv[j], lane + 30);
        sv[j] = v;
    }
    const bool ol = lane < 10;
    float m4 = -1e30f;
    #pragma unroll
    for (int j = 0; j < 4; j++) {
        sv[j] = ol ? (0.25f * sv[j] + b2[lane * 4 + j]) : -1e30f;
        m4 = fmaxf(m4, sv[j]);
    }
    #pragma unroll
    for (int d = 1; d < 16; d <<= 1) m4 = fmaxf(m4, __shfl_xor(m4, d));
    float s = 0.f;
    #pragma unroll
    for (int j = 0; j < 4; j++) s += ol ? __expf(sv[j] - m4) : 0.f;
    #pragma unroll
    for (int d = 1; d < 16; d <<= 1) s += __shfl_xor(s, d);
    float ls = logf(s);
    if (ol) {
        float4 o = make_float4(sv[0] - m4 - ls, sv[1] - m4 - ls, sv[2] - m4 - ls, sv[3] - m4 - ls);
        *(float4*)&outp[(size_t)n * 40 + lane * 4] = o;
    }
}

// ---------------- BN stats stage 1: per-block partials (NO atomics) ----------------
__global__ __launch_bounds__(256) void k_bnstats1(const unsigned short* __restrict__ X,
        float* __restrict__ ps, float* __restrict__ pq) {
    __shared__ float lds[4 * 256];
    const int tid = threadIdx.x;
    const int colg = (tid & 63) * 4;
    const int w = tid >> 6;
    float s[4] = {0.f, 0.f, 0.f, 0.f}, q[4] = {0.f, 0.f, 0.f, 0.f};
    for (int r = blockIdx.x * 4 + w; r < NN; r += NBS * 4) {
        ushort4 hv = *(const ushort4*)&X[(size_t)r * 256 + colg];
        const unsigned short hh[4] = {hv.x, hv.y, hv.z, hv.w};
        #pragma unroll
        for (int j = 0; j < 4; j++) { float v = bf2f(hh[j]); s[j] += v; q[j] += v * v; }
    }
    #pragma unroll
    for (int j = 0; j < 4; j++) lds[w * 256 + colg + j] = s[j];
    __syncthreads();
    float ts = lds[tid] + lds[256 + tid] + lds[512 + tid] + lds[768 + tid];
    __syncthreads();
    #pragma unroll
    for (int j = 0; j < 4; j++) lds[w * 256 + colg + j] = q[j];
    __syncthreads();
    float tq = lds[tid] + lds[256 + tid] + lds[512 + tid] + lds[768 + tid];
    ps[(size_t)blockIdx.x * 256 + tid] = ts;
    pq[(size_t)blockIdx.x * 256 + tid] = tq;
}

// ---------------- BN stats stage 2: reduce partials -> sc/sh per column ----------------
__global__ __launch_bounds__(256) void k_bnred(const float* __restrict__ ps,
        const float* __restrict__ pq, const float* __restrict__ g,
        const float* __restrict__ beta, float* __restrict__ sc_o, float* __restrict__ sh_o) {
    const int col = blockIdx.x, tid = threadIdx.x;
    float s = ps[(size_t)tid * 256 + col] + ps[(size_t)(tid + 256) * 256 + col];
    float q = pq[(size_t)tid * 256 + col] + pq[(size_t)(tid + 256) * 256 + col];
    #pragma unroll
    for (int d = 1; d < 64; d <<= 1) { s += __shfl_xor(s, d); q += __shfl_xor(q, d); }
    __shared__ float ls[4], lq[4];
    if ((tid & 63) == 0) { ls[tid >> 6] = s; lq[tid >> 6] = q; }
    __syncthreads();
    if (tid == 0) {
        float S = ls[0] + ls[1] + ls[2] + ls[3];
        float Q = lq[0] + lq[1] + lq[2] + lq[3];
        const float inv = 1.f / (float)NN;
        float mu = S * inv;
        float var = Q * inv - mu * mu;
        float sc = rsqrtf(var + 1e-5f) * g[col];
        sc_o[col] = sc;
        sh_o[col] = beta[col] - mu * sc;             // GAT bias b cancels under BN
    }
}

// ---------------- BN apply + ELU in-place (bf16) + NEXT layer's es/ed ----------------
__global__ __launch_bounds__(256) void k_bnapply(unsigned short* __restrict__ X,
        const float* __restrict__ sc_i, const float* __restrict__ sh_i,
        const float* __restrict__ vs, const float* __restrict__ vd,
        float4* __restrict__ es4, float4* __restrict__ ed4) {
    const int hl = threadIdx.x & 31;
    const int colg = hl * 8;
    const int rowo = threadIdx.x >> 5;
    float sc[8], sh[8];
    #pragma unroll
    for (int j = 0; j < 8; j++) { sc[j] = sc_i[colg + j]; sh[j] = sh_i[colg + j]; }
    for (int r = blockIdx.x * 8 + rowo; r < NN; r += gridDim.x * 8) {
        uint4 u = *(uint4*)&X[(size_t)r * 256 + colg];
        unsigned int uu[4] = {u.x, u.y, u.z, u.w};
        unsigned int oo[4];
        float s[4] = {0.f, 0.f, 0.f, 0.f}, dd[4] = {0.f, 0.f, 0.f, 0.f};
        #pragma unroll
        for (int p = 0; p < 4; p++) {
            float lo = lo2f(uu[p]);
            float hi = hi2f(uu[p]);
            float vlo = lo * sc[p * 2] + sh[p * 2];
            float vhi = hi * sc[p * 2 + 1] + sh[p * 2 + 1];
            vlo = (vlo > 0.f) ? vlo : expm1f(vlo);
            vhi = (vhi > 0.f) ? vhi : expm1f(vhi);
            oo[p] = (unsigned int)f2bf(vlo) | ((unsigned int)f2bf(vhi) << 16);
            // next-layer logits contribution
            float4 a0 = *(const float4*)&vs[(colg + 2 * p) * 4];
            float4 b0 = *(const float4*)&vd[(colg + 2 * p) * 4];
            float4 a1 = *(const float4*)&vs[(colg + 2 * p + 1) * 4];
            float4 b1 = *(const float4*)&vd[(colg + 2 * p + 1) * 4];
            s[0] += vlo * a0.x + vhi * a1.x; s[1] += vlo * a0.y + vhi * a1.y;
            s[2] += vlo * a0.z + vhi * a1.z; s[3] += vlo * a0.w + vhi * a1.w;
            dd[0] += vlo * b0.x + vhi * b1.x; dd[1] += vlo * b0.y + vhi * b1.y;
            dd[2] += vlo * b0.z + vhi * b1.z; dd[3] += vlo * b0.w + vhi * b1.w;
        }
        *(uint4*)&X[(size_t)r * 256 + colg] = make_uint4(oo[0], oo[1], oo[2], oo[3]);
        #pragma unroll
        for (int d = 1; d < 32; d <<= 1) {
            #pragma unroll
            for (int j = 0; j < 4; j++) { s[j] += __shfl_xor(s[j], d); dd[j] += __shfl_xor(dd[j], d); }
        }
        if (hl == 0) {
            es4[r] = make_float4(s[0], s[1], s[2], s[3]);
            ed4[r] = make_float4(dd[0], dd[1], dd[2], dd[3]);
        }
    }
}

extern "C" void kernel_launch(void* const* d_in, const int* in_sizes, int n_in,
                              void* d_out, int out_size, void* d_ws, size_t ws_size,
                              hipStream_t stream) {
    const float* x   = (const float*)d_in[0];
    const int*   ei  = (const int*)d_in[1];
    const float* W0  = (const float*)d_in[2];
    const float* as0 = (const float*)d_in[3];
    const float* ad0 = (const float*)d_in[4];
    const float* g0  = (const float*)d_in[6];
    const float* be0 = (const float*)d_in[7];
    const float* W1  = (const float*)d_in[8];
    const float* as1 = (const float*)d_in[9];
    const float* ad1 = (const float*)d_in[10];
    const float* g1  = (const float*)d_in[12];
    const float* be1 = (const float*)d_in[13];
    const float* W2  = (const float*)d_in[14];
    const float* as2 = (const float*)d_in[15];
    const float* ad2 = (const float*)d_in[16];
    const float* b2  = (const float*)d_in[17];
    float* out = (float*)d_out;

    char* w = (char*)d_ws;
    size_t off = 0;
    auto take = [&](size_t bytes) -> void* {
        off = (off + 255) & ~(size_t)255;
        void* p = w + off; off += bytes; return p;
    };
    unsigned short* Agg16 = (unsigned short*)take((size_t)NN * 256 * 2);  // agg out / BN in-place
    unsigned short* xb    = (unsigned short*)take((size_t)NN * 128 * 2);
    unsigned char*  H8    = (unsigned char*)take((size_t)NN * 256);       // fp8 H: L0/L1 stride 256B, L2 stride 192B
    float* es     = (float*)take((size_t)NN * 4 * 4);
    float* ed     = (float*)take((size_t)NN * 4 * 4);
    int*   counts = (int*)take((size_t)NN * 4);
    int*   indptr = (int*)take((size_t)(NN + 1) * 4);
    int*   lps    = (int*)take((size_t)NEP * 4);
    int*   srcs   = (int*)take((size_t)NEP * 4);
    int*   dstc   = (int*)take((size_t)NEP * 4);
    uint2* wq     = (uint2*)take((size_t)NEP * 8);
    int*   bsum   = (int*)take(64 * 4);
    unsigned short* Wt0 = (unsigned short*)take((size_t)256 * 128 * 2);
    unsigned short* Wt1 = (unsigned short*)take((size_t)256 * 256 * 2);
    unsigned short* Wt2 = (unsigned short*)take((size_t)192 * 256 * 2);
    float* vs0 = (float*)take(128 * 4 * 4);
    float* vd0 = (float*)take(128 * 4 * 4);
    float* vs1 = (float*)take(256 * 4 * 4);
    float* vd1 = (float*)take(256 * 4 * 4);
    float* vs2 = (float*)take(256 * 4 * 4);
    float* vd2 = (float*)take(256 * 4 * 4);
    float* ps  = (float*)take((size_t)NBS * 256 * 4);
    float* pq  = (float*)take((size_t)NBS * 256 * 4);
    float* bns = (float*)take(512 * 4);                  // sc[256] | sh[256]

    k_wv<<<640, 256, 0, stream>>>(W0, as0, ad0, W1, as1, ad1, W2, as2, ad2,
                                  vs0, vd0, vs1, vd1, vs2, vd2);
    hipMemsetAsync(counts, 0, (size_t)NN * 4, stream);
    k_prep<<<GPREP, 256, 0, stream>>>(x, xb, W0, Wt0, W1, Wt1, W2, Wt2,
                                      vs0, vd0, (float4*)es, (float4*)ed);

    // ---- layer 0 GEMM + CSR pass-1 (independent; co-scheduled) ----
    k_gemm<128, 256, 256, true><<<GMAT + GEDGE, 256, 0, stream>>>(xb, Wt0, H8,
            nullptr, nullptr, nullptr, nullptr, nullptr, ei, counts, lps);

    k_scan1<<<SCB, 256, 0, stream>>>(counts, indptr, bsum);
    k_scan2<<<1, 64, 0, stream>>>(bsum, indptr);
    k_scan3<<<SCB, 256, 0, stream>>>(indptr, bsum);
    k_place<<<GEDGE + GWAVE, 256, 0, stream>>>(ei, indptr, lps, srcs, dstc);
    k_wgt<<<GEDGE, 256, 0, stream>>>((const float4*)es, (const float4*)ed, srcs, dstc, wq);

    // ---- layer 0 remainder ----
    k_agg<<<GWAVE, 256, 0, stream>>>(H8, wq, indptr, srcs, Agg16);
    k_bnstats1<<<NBS, 256, 0, stream>>>(Agg16, ps, pq);
    k_bnred<<<256, 256, 0, stream>>>(ps, pq, g0, be0, bns, bns + 256);
    k_bnapply<<<1024, 256, 0, stream>>>(Agg16, bns, bns + 256, vs1, vd1,
                                        (float4*)es, (float4*)ed);

    // ---- layer 1 ----  (gemm + fused edge weights)
    k_gemm<256, 256, 256, false><<<GMAT + GEDGE, 256, 0, stream>>>(Agg16, Wt1, H8,
            (const float4*)es, (const float4*)ed, srcs, dstc, wq, nullptr, nullptr, nullptr);
    k_agg<<<GWAVE, 256, 0, stream>>>(H8, wq, indptr, srcs, Agg16);
    k_bnstats1<<<NBS, 256, 0, stream>>>(Agg16, ps, pq);
    k_bnred<<<256, 256, 0, stream>>>(ps, pq, g1, be1, bns, bns + 256);
    k_bnapply<<<1024, 256, 0, stream>>>(Agg16, bns, bns + 256, vs2, vd2,
                                        (float4*)es, (float4*)ed);

    // ---- layer 2 ----  (H in fp8, row stride 192B, 160 cols used)
    k_gemm<256, 192, 160, false><<<GMAT + GEDGE, 256, 0, stream>>>(Agg16, Wt2, H8,
            (const float4*)es, (const float4*)ed, srcs, dstc, wq, nullptr, nullptr, nullptr);
    k_agg2<<<GWAVE, 256, 0, stream>>>(H8, wq, indptr, srcs, b2, out);
}